// Round 3
// 782.309 us; speedup vs baseline: 1.0003x; 1.0003x over previous
//
#include <hip/hip_runtime.h>
#include <cmath>

// Problem constants
#define NB 8
#define NPTS 4096
#define NPT 1024
#define NSAMP 32
#define MTOT (NB*NPT*NSAMP)   // 262144 rows for the MLP
#define NBLK 4096             // MTOT/64 GEMM blocks

typedef float v2f __attribute__((ext_vector_type(2)));
typedef _Float16 half8 __attribute__((ext_vector_type(8)));
typedef float f32x4 __attribute__((ext_vector_type(4)));

__device__ __forceinline__ unsigned int pk2h(float a, float b) {
  _Float16 ha = (_Float16)a, hb = (_Float16)b;          // v_cvt_f16_f32 (RNE)
  unsigned short ua = __builtin_bit_cast(unsigned short, ha);
  unsigned short ub = __builtin_bit_cast(unsigned short, hb);
  return (unsigned int)ua | ((unsigned int)ub << 16);
}
__device__ __forceinline__ unsigned short f2h(float v) {
  _Float16 h = (_Float16)v;
  return __builtin_bit_cast(unsigned short, h);
}

// ---------------------------------------------------------------------------
// Stage 1: farthest point sampling. One block of 4 waves per batch (r8:
// 256 threads, 16 pts/lane). Rationale: the 512-thread r6 design was
// issue-bound at 2 waves/SIMD (~800 issue-cyc/SIMD/step of near-identical
// instruction streams). 1 wave/SIMD halves per-SIMD issue; 4-key cross-wave
// tree (1 ulonglong2[2] read + 3 u64 maxes) and 4-wave barrier shrink the
// serial tail. Bitwise-exact f32 replication of the reference: contract(off),
// (dx*dx+dy*dy)+dz*dz order, key=(maxbits<<32)|~idx for first-index argmax
// tie-break. No dynamically-indexed local arrays (r7: scratch spill).
// ---------------------------------------------------------------------------
__global__ __launch_bounds__(256) void fps_kernel(const float* __restrict__ xyz,
                                                  float* __restrict__ new_xyz) {
#pragma clang fp contract(off)
  const int b = blockIdx.x;
  const int t = threadIdx.x;          // 0..255
  const int wv = t >> 6;              // 0..3
  const int lane = t & 63;
  __shared__ float4 sxyz[NPTS];                  // 64 KiB
  __shared__ float4 sout[NPT];                   // 16 KiB centroid history
  __shared__ unsigned long long skey[2][4];      // parity-buffered wave keys
  const float* X = xyz + (size_t)b * NPTS * 3;
  v2f px[8], py[8], pz[8], dist[8];
#pragma unroll
  for (int i = 0; i < 8; ++i) {
    int p0 = (2 * i) * 256 + t;
    int p1 = (2 * i + 1) * 256 + t;
    float x0 = X[p0 * 3 + 0], y0 = X[p0 * 3 + 1], z0 = X[p0 * 3 + 2];
    float x1 = X[p1 * 3 + 0], y1 = X[p1 * 3 + 1], z1 = X[p1 * 3 + 2];
    px[i] = (v2f){x0, x1}; py[i] = (v2f){y0, y1}; pz[i] = (v2f){z0, z1};
    sxyz[p0] = make_float4(x0, y0, z0, 0.0f);
    sxyz[p1] = make_float4(x1, y1, z1, 0.0f);
    dist[i] = (v2f){1e10f, 1e10f};
  }
  __syncthreads();
  float ccx = X[0], ccy = X[1], ccz = X[2];      // first centroid = point 0
  for (int s = 0; s < NPT; ++s) {
    if (t == 0) sout[s] = make_float4(ccx, ccy, ccz, 0.0f);
    v2f cx = (v2f){ccx, ccx}, cy = (v2f){ccy, ccy}, cz = (v2f){ccz, ccz};
    v2f nd[8];
#pragma unroll
    for (int i = 0; i < 8; ++i) {
      v2f dx = px[i] - cx;
      v2f dy = py[i] - cy;
      v2f dz = pz[i] - cz;
      v2f d = (dx * dx + dy * dy) + dz * dz;     // contract(off): ref order
      v2f m = __builtin_elementwise_min(dist[i], d);
      dist[i] = m;
      nd[i] = m;
    }
    v2f t01 = __builtin_elementwise_max(nd[0], nd[1]);
    v2f t23 = __builtin_elementwise_max(nd[2], nd[3]);
    v2f t45 = __builtin_elementwise_max(nd[4], nd[5]);
    v2f t67 = __builtin_elementwise_max(nd[6], nd[7]);
    v2f t03 = __builtin_elementwise_max(t01, t23);
    v2f t47 = __builtin_elementwise_max(t45, t67);
    v2f t07 = __builtin_elementwise_max(t03, t47);
    float lmax = fmaxf(t07.x, t07.y);
    unsigned km = __float_as_uint(lmax);
    {
      unsigned o;
      o = (unsigned)__builtin_amdgcn_update_dpp(0, (int)km, 0x111, 0xf, 0xf, false);
      km = o > km ? o : km;   // row_shr:1
      o = (unsigned)__builtin_amdgcn_update_dpp(0, (int)km, 0x112, 0xf, 0xf, false);
      km = o > km ? o : km;   // row_shr:2
      o = (unsigned)__builtin_amdgcn_update_dpp(0, (int)km, 0x114, 0xf, 0xf, false);
      km = o > km ? o : km;   // row_shr:4
      o = (unsigned)__builtin_amdgcn_update_dpp(0, (int)km, 0x118, 0xf, 0xf, false);
      km = o > km ? o : km;   // row_shr:8
      o = (unsigned)__builtin_amdgcn_update_dpp(0, (int)km, 0x142, 0xf, 0xf, false);
      km = o > km ? o : km;   // row_bcast:15
      o = (unsigned)__builtin_amdgcn_update_dpp(0, (int)km, 0x143, 0xf, 0xf, false);
      km = o > km ? o : km;   // row_bcast:31
    }
    unsigned wmax = (unsigned)__builtin_amdgcn_readlane((int)km, 63);  // uniform
    unsigned long long m0  = __ballot(__float_as_uint(nd[0].x) == wmax);
    unsigned long long m1  = __ballot(__float_as_uint(nd[0].y) == wmax);
    unsigned long long m2  = __ballot(__float_as_uint(nd[1].x) == wmax);
    unsigned long long m3  = __ballot(__float_as_uint(nd[1].y) == wmax);
    unsigned long long m4  = __ballot(__float_as_uint(nd[2].x) == wmax);
    unsigned long long m5  = __ballot(__float_as_uint(nd[2].y) == wmax);
    unsigned long long m6  = __ballot(__float_as_uint(nd[3].x) == wmax);
    unsigned long long m7  = __ballot(__float_as_uint(nd[3].y) == wmax);
    unsigned long long m8  = __ballot(__float_as_uint(nd[4].x) == wmax);
    unsigned long long m9  = __ballot(__float_as_uint(nd[4].y) == wmax);
    unsigned long long m10 = __ballot(__float_as_uint(nd[5].x) == wmax);
    unsigned long long m11 = __ballot(__float_as_uint(nd[5].y) == wmax);
    unsigned long long m12 = __ballot(__float_as_uint(nd[6].x) == wmax);
    unsigned long long m13 = __ballot(__float_as_uint(nd[6].y) == wmax);
    unsigned long long m14 = __ballot(__float_as_uint(nd[7].x) == wmax);
    unsigned long long m15 = __ballot(__float_as_uint(nd[7].y) == wmax);
    unsigned long long mk = m15; int ord = 15;
    if (m14) { mk = m14; ord = 14; }
    if (m13) { mk = m13; ord = 13; }
    if (m12) { mk = m12; ord = 12; }
    if (m11) { mk = m11; ord = 11; }
    if (m10) { mk = m10; ord = 10; }
    if (m9)  { mk = m9;  ord = 9; }
    if (m8)  { mk = m8;  ord = 8; }
    if (m7)  { mk = m7;  ord = 7; }
    if (m6)  { mk = m6;  ord = 6; }
    if (m5)  { mk = m5;  ord = 5; }
    if (m4)  { mk = m4;  ord = 4; }
    if (m3)  { mk = m3;  ord = 3; }
    if (m2)  { mk = m2;  ord = 2; }
    if (m1)  { mk = m1;  ord = 1; }
    if (m0)  { mk = m0;  ord = 0; }
    int wlane = (int)__builtin_ctzll(mk);
    int idx = ord * 256 + wv * 64 + wlane;
    unsigned long long key = ((unsigned long long)wmax << 32)
                           | (unsigned int)(~idx);
    int par = s & 1;
    if (lane == 0) skey[par][wv] = key;
    __syncthreads();
    const ulonglong2* sk = (const ulonglong2*)skey[par];
    ulonglong2 A = sk[0], B = sk[1];
    unsigned long long a = A.x > A.y ? A.x : A.y;
    unsigned long long bq = B.x > B.y ? B.x : B.y;
    unsigned long long kf = a > bq ? a : bq;
    int far = (int)(~(unsigned int)kf) & (NPTS - 1);
    float4 cc = sxyz[far];
    ccx = cc.x; ccy = cc.y; ccz = cc.z;
  }
  __syncthreads();
  float* outp = new_xyz + (size_t)b * NPT * 3;
  for (int j = t; j < NPT; j += 256) {
    float4 c = sout[j];
    outp[3 * j + 0] = c.x; outp[3 * j + 1] = c.y; outp[3 * j + 2] = c.z;
  }
}

// ---------------------------------------------------------------------------
// Stage 2: ball query (blocks 0..2047) + weight prep (blocks 2048..2127).
// Ball query: one wave per (b,s), first 32 in-index-order hits, pad w/ first.
// Weight prep: fp32 -> fp16, [o][k] layout with k padded to the LDS stride;
// Wt1 bakes in the L1 permutation [pts64|dxyz3|0-pad].
// ---------------------------------------------------------------------------
__global__ __launch_bounds__(256) void ballq_prep(
    const float* __restrict__ xyz, const float* __restrict__ new_xyz,
    int* __restrict__ gidx,
    const float* __restrict__ w0, const float* __restrict__ w1,
    const float* __restrict__ w2, unsigned short* __restrict__ Wt1,
    unsigned short* __restrict__ Wt2, unsigned short* __restrict__ Wt3) {
  if (blockIdx.x >= 2048) {
    int i = (blockIdx.x - 2048) * 256 + threadIdx.x;   // 0..20479
    if (i < 64 * 104) {
      int o = i / 104, k = i - o * 104;
      float v = 0.0f;
      if (k < 64) v = w0[o * 67 + k + 3];
      else if (k < 67) v = w0[o * 67 + (k - 64)];
      Wt1[i] = f2h(v);
    } else if (i < 64 * 104 + 64 * 72) {
      int j = i - 64 * 104;
      int o = j / 72, k = j - o * 72;
      Wt2[j] = (k < 64) ? f2h(w1[o * 64 + k]) : (unsigned short)0;
    } else {
      int l = i - 64 * 104 - 64 * 72;
      int o = l / 72, k = l - o * 72;
      Wt3[l] = (k < 64) ? f2h(w2[o * 64 + k]) : (unsigned short)0;
    }
    return;
  }
  int w = (blockIdx.x * 256 + threadIdx.x) >> 6;   // 8192 waves
  int lane = threadIdx.x & 63;
  int b = w >> 10;
  const float* X = xyz + (size_t)b * NPTS * 3;
  float cx = new_xyz[w * 3 + 0], cy = new_xyz[w * 3 + 1], cz = new_xyz[w * 3 + 2];
  int* out = gidx + (size_t)w * NSAMP;
  int cnt = 0, first = -1;
  for (int c = 0; c < NPTS / 64; ++c) {
    int p = c * 64 + lane;
    float dx = __fsub_rn(X[p * 3 + 0], cx);
    float dy = __fsub_rn(X[p * 3 + 1], cy);
    float dz = __fsub_rn(X[p * 3 + 2], cz);
    float d = __fadd_rn(__fadd_rn(__fmul_rn(dx, dx), __fmul_rn(dy, dy)), __fmul_rn(dz, dz));
    bool inr = !(d > 0.04f);   // f32(0.2**2) == 0.04f
    unsigned long long mask = __ballot(inr);
    if (mask) {
      if (first < 0) first = c * 64 + (int)__builtin_ctzll(mask);
      if (inr) {
        int pos = cnt + (int)__builtin_popcountll(mask & ((1ull << lane) - 1ull));
        if (pos < NSAMP) out[pos] = p;
      }
      cnt += (int)__builtin_popcountll(mask);
      if (cnt >= NSAMP) break;
    }
  }
  if (lane >= cnt && lane < NSAMP) out[lane] = first;
}

// ---------------------------------------------------------------------------
// Stage 4: MFMA (fp16 in, fp32 accum) MLP GEMM. 256 thr = 4 waves, 64-row
// tile; wave w owns rows 16w..16w+15. 16x16x32_f16 MFMAs; A[m=lane&15]
// [k=quad*8+j], B[k][n=lane&15] — both contiguous 16B LDS reads.
// C/D: row=quad*4+reg, col=lane&15 (HW-verified).
// MODE 0 (GATHER): L1 fused gather from f32 sources, K=67 padded to 96;
//   writes Y fp16. MODE 1 (MID): reads fp16 Y, applies prev BN+ReLU in
//   packed fp16 (adh = fp16 a|d), writes Y fp16. MODE 2 (LAST): like MID
//   but max/min-pools fp32 pre-activations over 32-row groups.
// BN stats always from the fp32 accumulators (pre-store) — fp16 storage
// does not touch the stats path.
// ---------------------------------------------------------------------------
template<int KB, int KS, int O, int MODE>
__global__ __launch_bounds__(256) void mfma_gemm(
    const unsigned short* __restrict__ Xh, const float* __restrict__ xyz,
    const float* __restrict__ points, const float* __restrict__ new_xyz,
    const int* __restrict__ gidx, const unsigned short* __restrict__ Wt,
    const float* __restrict__ bias, const unsigned short* __restrict__ adh,
    unsigned short* __restrict__ Yout, float* __restrict__ partials,
    float* __restrict__ mm_out) {
  constexpr int NT = O / 16;
  constexpr bool WRITE_Y = (MODE != 2);
  constexpr bool DO_MM = (MODE == 2);
  __shared__ __align__(16) unsigned short sA[64 * KS];
  __shared__ __align__(16) unsigned short sB[O * KS];
  const int t = threadIdx.x;
  const int wv = t >> 6, lane = t & 63;
  const int ml = lane & 15, qd = lane >> 4;
  const int m0 = blockIdx.x * 64;

  // stage B: straight uint4 copy of pre-converted weights
  {
    const uint4* src = (const uint4*)Wt;
    uint4* dst = (uint4*)sB;
    constexpr int NB4 = O * KS / 8;
    for (int i = t; i < NB4; i += 256) dst[i] = src[i];
  }
  // stage A
  if constexpr (MODE == 0) {
    int r = t >> 2, q = t & 3;          // 4 threads/row, 24 k each (KP=96)
    int m = m0 + r;
    int idx = gidx[m];
    int b = m >> 15;
    const float* prow = points + ((size_t)b * NPTS + idx) * 64;
    unsigned int pk[12];
    if (q < 2) {
#pragma unroll
      for (int j = 0; j < 6; ++j) {
        float4 v = *(const float4*)(prow + q * 24 + 4 * j);
        pk[2 * j] = pk2h(v.x, v.y);
        pk[2 * j + 1] = pk2h(v.z, v.w);
      }
    } else if (q == 2) {                 // k 48..71: pts 48-63, dxyz, zeros
#pragma unroll
      for (int j = 0; j < 4; ++j) {
        float4 v = *(const float4*)(prow + 48 + 4 * j);
        pk[2 * j] = pk2h(v.x, v.y);
        pk[2 * j + 1] = pk2h(v.z, v.w);
      }
      int g = m >> 5;
      const float* xr = xyz + ((size_t)b * NPTS + idx) * 3;
      float dx = __fsub_rn(xr[0], new_xyz[g * 3 + 0]);
      float dy = __fsub_rn(xr[1], new_xyz[g * 3 + 1]);
      float dz = __fsub_rn(xr[2], new_xyz[g * 3 + 2]);
      pk[8] = pk2h(dx, dy);
      pk[9] = pk2h(dz, 0.0f);
      pk[10] = 0; pk[11] = 0;
    } else {                             // k 72..95: zero pad
#pragma unroll
      for (int j = 0; j < 12; ++j) pk[j] = 0;
    }
    uint4* dst = (uint4*)&sA[r * KS + q * 24];
    dst[0] = make_uint4(pk[0], pk[1], pk[2], pk[3]);
    dst[1] = make_uint4(pk[4], pk[5], pk[6], pk[7]);
    dst[2] = make_uint4(pk[8], pk[9], pk[10], pk[11]);
  } else {
    // fp16 input + packed-fp16 BN+ReLU (a,d from adh; exact relu in fp16)
    int r = t >> 2, q = t & 3;          // 4 threads/row, 16 halves each
    const unsigned short* src = Xh + (size_t)(m0 + r) * 64 + q * 16;
    uint4 y0 = *(const uint4*)(src);
    uint4 y1 = *(const uint4*)(src + 8);
    uint4 a0 = *(const uint4*)(adh + q * 16);
    uint4 a1 = *(const uint4*)(adh + q * 16 + 8);
    uint4 d0 = *(const uint4*)(adh + 128 + q * 16);
    uint4 d1 = *(const uint4*)(adh + 128 + q * 16 + 8);
    half8 yv0 = __builtin_bit_cast(half8, y0);
    half8 yv1 = __builtin_bit_cast(half8, y1);
    half8 av0 = __builtin_bit_cast(half8, a0);
    half8 av1 = __builtin_bit_cast(half8, a1);
    half8 dv0 = __builtin_bit_cast(half8, d0);
    half8 dv1 = __builtin_bit_cast(half8, d1);
    half8 z = (half8)(_Float16)0.0f;
    half8 r0 = __builtin_elementwise_max(av0 * yv0 + dv0, z);
    half8 r1 = __builtin_elementwise_max(av1 * yv1 + dv1, z);
    uint4* dst = (uint4*)&sA[r * KS + q * 16];
    dst[0] = __builtin_bit_cast(uint4, r0);
    dst[1] = __builtin_bit_cast(uint4, r1);
  }
  __syncthreads();

  f32x4 acc[NT];
#pragma unroll
  for (int nt = 0; nt < NT; ++nt) acc[nt] = f32x4{0.0f, 0.0f, 0.0f, 0.0f};

#pragma unroll
  for (int kb = 0; kb < KB; ++kb) {
    int kof = kb * 32 + qd * 8;
    uint4 au = *(const uint4*)&sA[(16 * wv + ml) * KS + kof];
    half8 af = __builtin_bit_cast(half8, au);
#pragma unroll
    for (int nt = 0; nt < NT; ++nt) {
      uint4 bu = *(const uint4*)&sB[(nt * 16 + ml) * KS + kof];
      half8 bf = __builtin_bit_cast(half8, bu);
      acc[nt] = __builtin_amdgcn_mfma_f32_16x16x32_f16(af, bf, acc[nt], 0, 0, 0);
    }
  }
  // bias (fp32)
#pragma unroll
  for (int nt = 0; nt < NT; ++nt) {
    float bb = bias[nt * 16 + ml];
    acc[nt][0] += bb; acc[nt][1] += bb; acc[nt][2] += bb; acc[nt][3] += bb;
  }
  // per-lane stats over its 4 rows, then quad-reduce via shuffles (fp32)
  float s1[NT], s2[NT];
#pragma unroll
  for (int nt = 0; nt < NT; ++nt) {
    f32x4 a4 = acc[nt];
    s1[nt] = (a4[0] + a4[1]) + (a4[2] + a4[3]);
    s2[nt] = (a4[0] * a4[0] + a4[1] * a4[1]) + (a4[2] * a4[2] + a4[3] * a4[3]);
    s1[nt] += __shfl_down(s1[nt], 32, 64);
    s1[nt] += __shfl_down(s1[nt], 16, 64);
    s2[nt] += __shfl_down(s2[nt], 32, 64);
    s2[nt] += __shfl_down(s2[nt], 16, 64);
  }
  if constexpr (WRITE_Y) {
#pragma unroll
    for (int nt = 0; nt < NT; ++nt)
#pragma unroll
      for (int r = 0; r < 4; ++r)
        Yout[(size_t)(m0 + 16 * wv + qd * 4 + r) * 64 + nt * 16 + ml] =
            f2h(acc[nt][r]);
  }
  float mx[NT], mn[NT];
  if constexpr (DO_MM) {
#pragma unroll
    for (int nt = 0; nt < NT; ++nt) {
      f32x4 a4 = acc[nt];
      mx[nt] = fmaxf(fmaxf(a4[0], a4[1]), fmaxf(a4[2], a4[3]));
      mn[nt] = fminf(fminf(a4[0], a4[1]), fminf(a4[2], a4[3]));
      mx[nt] = fmaxf(mx[nt], __shfl_down(mx[nt], 32, 64));
      mx[nt] = fmaxf(mx[nt], __shfl_down(mx[nt], 16, 64));
      mn[nt] = fminf(mn[nt], __shfl_down(mn[nt], 32, 64));
      mn[nt] = fminf(mn[nt], __shfl_down(mn[nt], 16, 64));
    }
  }
  __syncthreads();                       // frag reads done; reuse sA as scratch
  float* scr = (float*)sA;
  if (qd == 0) {
#pragma unroll
    for (int nt = 0; nt < NT; ++nt) {
      scr[wv * O + nt * 16 + ml] = s1[nt];
      scr[4 * O + wv * O + nt * 16 + ml] = s2[nt];
    }
    if constexpr (DO_MM) {
#pragma unroll
      for (int nt = 0; nt < NT; ++nt) {
        scr[8 * O + wv * O + nt * 16 + ml] = mx[nt];
        scr[12 * O + wv * O + nt * 16 + ml] = mn[nt];
      }
    }
  }
  __syncthreads();
  if (t < O) {
    float a = (scr[t] + scr[O + t]) + (scr[2 * O + t] + scr[3 * O + t]);
    float b2 = (scr[4 * O + t] + scr[5 * O + t]) + (scr[6 * O + t] + scr[7 * O + t]);
    partials[(size_t)t * NBLK + blockIdx.x] = a;
    partials[(size_t)(O + t) * NBLK + blockIdx.x] = b2;
  }
  if constexpr (DO_MM) {
    int o = t & 127, g = t >> 7;         // waves {0,1}->group 0, {2,3}->group 1
    float gmx = fmaxf(scr[8 * O + (2 * g) * O + o], scr[8 * O + (2 * g + 1) * O + o]);
    float gmn = fminf(scr[12 * O + (2 * g) * O + o], scr[12 * O + (2 * g + 1) * O + o]);
    int row = (m0 >> 5) + g;
    mm_out[(size_t)row * O + o] = gmx;
    mm_out[(size_t)8192 * O + (size_t)row * O + o] = gmn;
  }
}

// ---------------------------------------------------------------------------
// BN finalize: reduce 4096 partials per channel -> (a, d), a=g*rsigma,
// d = bt - mu*a. Writes f32 ad (a at [0..O), d at [128..128+O)) and the
// packed fp16 copy adh (same layout) consumed by the fp16 staging path.
// ---------------------------------------------------------------------------
__global__ __launch_bounds__(256) void bn_finalize(const float* __restrict__ partials,
                                                   const float* __restrict__ g,
                                                   const float* __restrict__ bt,
                                                   float* __restrict__ ad,
                                                   unsigned short* __restrict__ adh,
                                                   int O) {
  int o = blockIdx.x, t = threadIdx.x;
  const float* p1 = partials + (size_t)o * NBLK;
  const float* p2 = partials + (size_t)(O + o) * NBLK;
  float s1 = 0.0f, s2 = 0.0f;
  for (int i = t; i < NBLK; i += 256) { s1 += p1[i]; s2 += p2[i]; }
  __shared__ float r1[4], r2[4];
#pragma unroll
  for (int off = 32; off >= 1; off >>= 1) {
    s1 += __shfl_down(s1, off, 64);
    s2 += __shfl_down(s2, off, 64);
  }
  if ((t & 63) == 0) { r1[t >> 6] = s1; r2[t >> 6] = s2; }
  __syncthreads();
  if (t == 0) {
    float S1 = (r1[0] + r1[1]) + (r1[2] + r1[3]);
    float S2 = (r2[0] + r2[1]) + (r2[2] + r2[3]);
    const float invM = 1.0f / (float)MTOT;
    float mu = S1 * invM;
    float var = S2 * invM - mu * mu;
    float rs = 1.0f / sqrtf(var + 1e-5f);
    float a = g[o] * rs;
    float dv = bt[o] - mu * a;
    ad[o] = a;
    ad[128 + o] = dv;
    adh[o] = f2h(a);
    adh[128 + o] = f2h(dv);
  }
}

// ---------------------------------------------------------------------------
// Final: new_points[(b,s),o] = relu(a * (a>=0 ? max : min) + d)   (all fp32)
// ---------------------------------------------------------------------------
__global__ __launch_bounds__(256) void final_kernel(const float* __restrict__ mm,
                                                    const float* __restrict__ ad,
                                                    float* __restrict__ out) {
  int gid = blockIdx.x * 256 + threadIdx.x;   // 8192*128 exactly
  int o = gid & 127;
  float a = ad[o], d = ad[128 + o];
  float y = (a >= 0.0f) ? mm[gid] : mm[8192 * 128 + gid];
  out[gid] = fmaxf(fmaf(a, y, d), 0.0f);
}

extern "C" void kernel_launch(void* const* d_in, const int* in_sizes, int n_in,
                              void* d_out, int out_size, void* d_ws, size_t ws_size,
                              hipStream_t stream) {
  (void)in_sizes; (void)n_in; (void)out_size; (void)ws_size;
  const float* xyz    = (const float*)d_in[0];
  const float* points = (const float*)d_in[1];
  const float* w0  = (const float*)d_in[2];
  const float* b0  = (const float*)d_in[3];
  const float* g0  = (const float*)d_in[4];
  const float* bt0 = (const float*)d_in[5];
  const float* w1  = (const float*)d_in[6];
  const float* b1  = (const float*)d_in[7];
  const float* g1  = (const float*)d_in[8];
  const float* bt1 = (const float*)d_in[9];
  const float* w2  = (const float*)d_in[10];
  const float* b2  = (const float*)d_in[11];
  const float* g2  = (const float*)d_in[12];
  const float* bt2 = (const float*)d_in[13];

  float* out      = (float*)d_out;
  float* new_xyz  = out;                 // 8*1024*3 = 24576 floats
  float* out_pts  = out + 24576;         // 8*1024*128 floats

  float* wsf  = (float*)d_ws;
  int*   gidx = (int*)d_ws;                          // 262144 ints
  unsigned short* Y1h = (unsigned short*)(wsf + 262144);      // MTOT*64 fp16
  unsigned short* Y2h = Y1h + (size_t)MTOT * 64;              // MTOT*64 fp16
  float* part = (float*)(Y2h + (size_t)MTOT * 64);            // 2*128*4096
  float* ad1  = part + 2 * 128 * NBLK;               // 256
  float* ad2  = ad1 + 256;
  float* ad3  = ad2 + 256;
  unsigned short* adh1 = (unsigned short*)(ad3 + 256);        // 256
  unsigned short* adh2 = adh1 + 256;
  unsigned short* adh3 = adh2 + 256;
  float* mm   = (float*)(adh3 + 256);                // 2*8192*128
  unsigned short* Wt1 = (unsigned short*)(mm + 2 * 8192 * 128);  // 64*104
  unsigned short* Wt2 = Wt1 + 64 * 104;                          // 64*72
  unsigned short* Wt3 = Wt2 + 64 * 72;                           // 128*72

  fps_kernel<<<NB, 256, 0, stream>>>(xyz, new_xyz);
  ballq_prep<<<2128, 256, 0, stream>>>(xyz, new_xyz, gidx,
                                       w0, w1, w2, Wt1, Wt2, Wt3);

  mfma_gemm<3, 104, 64, 0><<<NBLK, 256, 0, stream>>>(
      nullptr, xyz, points, new_xyz, gidx, Wt1, b0, nullptr, Y1h, part, nullptr);
  bn_finalize<<<64, 256, 0, stream>>>(part, g0, bt0, ad1, adh1, 64);

  mfma_gemm<2, 72, 64, 1><<<NBLK, 256, 0, stream>>>(
      Y1h, nullptr, nullptr, nullptr, nullptr, Wt2, b1, adh1, Y2h, part, nullptr);
  bn_finalize<<<64, 256, 0, stream>>>(part, g1, bt1, ad2, adh2, 64);

  mfma_gemm<2, 72, 128, 2><<<NBLK, 256, 0, stream>>>(
      Y2h, nullptr, nullptr, nullptr, nullptr, Wt3, b2, adh2, nullptr, part, mm);
  bn_finalize<<<128, 256, 0, stream>>>(part, g2, bt2, ad3, adh3, 128);

  final_kernel<<<(8192 * 128) / 256, 256, 0, stream>>>(mm, ad3, out_pts);
}